// Round 5
// baseline (565.024 us; speedup 1.0000x reference)
//
#include <hip/hip_runtime.h>

#define N_ATOM 30000
#define N_PAIR 1000000
#define N_TRI  4000000
#define N_SF   16
#define FP_ELEMS (N_ATOM * N_SF)

#define ASH  5                      // atoms per coarse bucket = 32
#define APB  32
#define NCB  938                    // ceil(30000/32)
#define NSUB 8                      // ik-SHARDS (qik/125000) == XCD via blockIdx%8
#define NSEG (NCB * NSUB)           // 7504
#define OVF_CNT_IDX NSEG
#define OVF_CAP 131072
#define TILE 4096
#define PER_TH 16
#define NTILES ((N_TRI + TILE - 1) / TILE)   // 977
#define WCAP 1280                   // LDS window cap (bucket pairs ~1067 +- 33)
#define LFB 2048                    // LDS ij-flag bitset (bits)

// workspace layout (bytes)
// [0, 167936) zeroed by zero_meta (ccnt + pcnt + pplace + pbase); flagbits too
#define OFF_CCNT   0ULL             // (NSEG+1) ints (reserve 32 KiB)
#define OFF_PCNT   32768ULL         // 938 counters, padded stride 16 ints
#define OFF_PPLACE 98304ULL         // 938 counters, padded stride 16 ints
#define OFF_PBASE  163840ULL        // 939 ints (exclusive bases + sentinel)
#define OFF_AMAP   196608ULL        // 4,000,000 B: per-pair {c:10|a5:5|lidx:17}
#define OFF_FLAGB  4196608ULL       // 131,072 B: ij-valid bit per permuted pair
#define OFF_OVF    4327680ULL       // 1,048,576 B: int2 * 131072
#define OFF_PACKS  5376256ULL       // 16,000,000 B: float4 {dx,dy,dz, bitcast(ikmax)}
#define OFF_CB     21376256ULL      // cbucket: NSEG * cap * 8
#define ZERO_INTS  41984            // 167,936 / 4
#define FLAGB_INTS 32768

__device__ __constant__ float c_eta[16] = {
    0.01f, 0.014f, 0.02f, 0.028f, 0.04f, 0.056f, 0.08f, 0.11f,
    0.16f, 0.22f, 0.32f, 0.45f, 0.63f, 0.72f, 0.9f, 1.0f};

// ---------------------------------------------------------------------------
// geometry math; fc recomputed from distances (pack.w carries the ik max)
__device__ __forceinline__ bool tri_math(
    float4 A, float4 B, float A8[8], float& R2)
{
    float ax = A.x, ay = A.y, az = A.z;
    float bx = B.x, by = B.y, bz = B.z;
    float d2ij = fmaf(ax, ax, fmaf(ay, ay, az * az));
    float d2ik = fmaf(bx, bx, fmaf(by, by, bz * bz));
    float jx = bx - ax, jy = by - ay, jz = bz - az;
    float d2jk = fmaf(jx, jx, fmaf(jy, jy, jz * jz));
    if (!(d2jk < 36.0f)) return false;
    float dij = sqrtf(d2ij);
    float dik = sqrtf(d2ik);
    float djk = sqrtf(d2jk);
    const float PI_OVER_RC = 0.5235987755982988f;
    float fcij = 0.5f * (__cosf(PI_OVER_RC * dij) + 1.0f);
    float fcik = 0.5f * (__cosf(PI_OVER_RC * dik) + 1.0f);
    float fcjk = 0.5f * (__cosf(PI_OVER_RC * djk) + 1.0f);
    float dot = fmaf(ax, bx, fmaf(ay, by, az * bz));
    float cosv = dot / (dij * dik);
    R2 = d2ij + d2ik + d2jk;
    float FCt = fcij * fcik * fcjk;
    float bm = fmaxf(1.0f - cosv, 0.0f);
    float bp = fmaxf(1.0f + cosv, 0.0f);
    float bm2 = bm * bm, bp2 = bp * bp;
    float bm4 = bm2 * bm2, bp4 = bp2 * bp2;
    float bm8 = bm4 * bm4, bp8 = bp4 * bp4;
    A8[0] = FCt * bm;               A8[1] = FCt * bp;
    A8[2] = 0.5f * FCt * bm2;       A8[3] = 0.5f * FCt * bp2;
    A8[4] = 0.125f * FCt * bm4;     A8[5] = 0.125f * FCt * bp4;
    A8[6] = 0.0078125f * FCt * bm8; A8[7] = 0.0078125f * FCt * bp8;
    return true;
}

__device__ __forceinline__ int qshard(int qik) {
    return (int)((unsigned)(qik * 8u) / 1000000u);   // 0..7, 125000 pairs/shard
}

// ---------------------------------------------------------------------------
// fast path
// ---------------------------------------------------------------------------

__global__ __launch_bounds__(256) void zero_meta(
    int* __restrict__ m, unsigned int* __restrict__ fb)
{
    int i = blockIdx.x * blockDim.x + threadIdx.x;
    if (i < ZERO_INTS) m[i] = 0;
    if (i < FLAGB_INTS) fb[i] = 0u;
}

// histogram pairs per coarse bucket (LDS-staged; padded global counters)
__global__ __launch_bounds__(256) void pair_hist(
    const int2* __restrict__ ind2, int* __restrict__ pcnt)
{
    __shared__ int h[NCB];
    for (int i = threadIdx.x; i < NCB; i += 256) h[i] = 0;
    __syncthreads();
    int stride = gridDim.x * 256;
    for (int p = blockIdx.x * 256 + threadIdx.x; p < N_PAIR; p += stride)
        atomicAdd(&h[ind2[p].x >> ASH], 1);
    __syncthreads();
    for (int i = threadIdx.x; i < NCB; i += 256) {
        int v = h[i];
        if (v) atomicAdd(&pcnt[i * 16], v);
    }
}

// exclusive prefix scan of the 938 bucket counts (single 1024-thread block)
__global__ __launch_bounds__(1024) void scan_bases(
    const int* __restrict__ pcnt, int* __restrict__ pbase)
{
    __shared__ int s[1024];
    int t = threadIdx.x;
    int v0 = (t < NCB) ? pcnt[t * 16] : 0;
    s[t] = v0;
    __syncthreads();
    for (int off = 1; off < 1024; off <<= 1) {
        int v = 0;
        if (t >= off) v = s[t - off];
        __syncthreads();
        s[t] += v;
        __syncthreads();
    }
    if (t < NCB) pbase[t] = s[t] - v0;     // exclusive
    if (t == 0) pbase[NCB] = N_PAIR;       // sentinel
}

// place pairs into bucket-permuted packs[] (w = bitcast(-1) running max);
// build amap; also zero the fp output rows
__global__ __launch_bounds__(256) void pair_place(
    const int2* __restrict__ ind2, const float* __restrict__ diff,
    const int* __restrict__ pbase, int* __restrict__ pplace,
    unsigned int* __restrict__ amap, float4* __restrict__ packs,
    float* __restrict__ out)
{
    int p = blockIdx.x * blockDim.x + threadIdx.x;
    if (p < FP_ELEMS) out[p] = 0.0f;
    if (p >= N_PAIR) return;
    int a = ind2[p].x;
    int c = a >> ASH;
    int l = atomicAdd(&pplace[c * 16], 1);
    int q = pbase[c] + l;
    amap[p] = ((unsigned)c << 22) | ((unsigned)(a & (APB - 1)) << 17) | (unsigned)l;
    float4 r;
    r.x = diff[3 * p + 0];
    r.y = diff[3 * p + 1];
    r.z = diff[3 * p + 2];
    r.w = __int_as_float(-1);
    packs[q] = r;
}

// LDS-staged counting scatter into (ij-bucket, ik-shard) segments.
// Entries carry {a5,lidx} for the ij side and the permuted index q for ik.
// Segment (c,s) only references packs[125000*s .. 125000*(s+1)) on its B side.
__global__ __launch_bounds__(256) void bin3(
    const int2* __restrict__ ind3, const unsigned int* __restrict__ amap,
    const int* __restrict__ pbase,
    int* __restrict__ ccnt, int2* __restrict__ cbucket,
    int2* __restrict__ ovf, int cap)
{
    __shared__ int lseg[NSEG];            // 30 KiB: count, then base (in-place)
    const int thr = threadIdx.x;
    const long long t0 = (long long)blockIdx.x * TILE;

    for (int i = thr; i < NSEG; i += 256) lseg[i] = 0;
    __syncthreads();

    unsigned int mij_r[PER_TH];
    int qik_r[PER_TH];
    int slot_r[PER_TH];
#pragma unroll
    for (int j = 0; j < PER_TH; ++j) {
        long long t = t0 + j * 256 + thr;
        unsigned int mij = 0; int qik = 0, s = -1;
        if (t < N_TRI) {
            int2 pr = ind3[t];
            mij = amap[pr.x];
            unsigned int mik = amap[pr.y];
            qik = pbase[mik >> 22] + (int)(mik & 0x1FFFF);
            s = atomicAdd(&lseg[(int)(mij >> 22) * NSUB + qshard(qik)], 1);
        }
        mij_r[j] = mij; qik_r[j] = qik; slot_r[j] = s;
    }
    __syncthreads();
    for (int i = thr; i < NSEG; i += 256) {
        int n = lseg[i];
        lseg[i] = n ? atomicAdd(&ccnt[i], n) : 0;   // in-place count -> base
    }
    __syncthreads();
#pragma unroll
    for (int j = 0; j < PER_TH; ++j) {
        long long t = t0 + j * 256 + thr;
        if (t >= N_TRI) continue;
        unsigned int mij = mij_r[j];
        int qik = qik_r[j];
        int idx = (int)(mij >> 22) * NSUB + qshard(qik);
        int slot = lseg[idx] + slot_r[j];
        if (slot < cap) {
            int2 e;
            e.x = (int)(mij & 0x3FFFFF);   // a5:5 | lidx:17
            e.y = qik;
            cbucket[(size_t)idx * cap + slot] = e;
        } else {
            int o = atomicAdd(&ccnt[OVF_CNT_IDX], 1);
            if (o < OVF_CAP) { int2 e; e.x = (int)mij; e.y = qik; ovf[o] = e; }
        }
    }
}

// one block per (ij-bucket, ik-shard) segment; blockIdx = c*8 + s so that with
// round-robin block->XCD dispatch, XCD s only runs shard-s blocks -> B-reads
// (packs[qik]) confined to a 2MB slice resident in that XCD's 4MB L2 ->
// latency-bound random misses become L2 hits. A side staged in LDS (coalesced
// stream). Conditional atomicMax on the colocated, L2-local ik word.
__global__ __launch_bounds__(256) void reduce4(
    const int* __restrict__ ccnt, const int2* __restrict__ cbucket, int cap,
    float4* __restrict__ packs, const int* __restrict__ pbase,
    unsigned int* __restrict__ flagbits, float* __restrict__ out)
{
    __shared__ float4 win[WCAP];
    __shared__ float lacc[APB * 17];      // +1 pad per atom row
    __shared__ unsigned int lflag[LFB / 32];
    const int seg = blockIdx.x;
    const int b = seg >> 3;               // coarse ij bucket
    const int thr = threadIdx.x;
    const int base = pbase[b];
    const int wlen = min(pbase[b + 1] - base, WCAP);

    for (int i = thr; i < APB * 17; i += 256) lacc[i] = 0.0f;
    if (thr < LFB / 32) lflag[thr] = 0u;
    for (int i = thr; i < wlen; i += 256) win[i] = packs[base + i];

    int n = min(ccnt[seg], cap);
    const int2* segp = cbucket + (size_t)seg * cap;
    int* pw = (int*)packs;
    __syncthreads();

    for (int j0 = 0; j0 < n; j0 += 512) {
        int i1 = j0 + thr;
        int i2 = i1 + 256;
        bool v1 = i1 < n, v2 = i2 < n;
        int2 e1 = segp[v1 ? i1 : n - 1];  // clamp: broadcast line, ~free
        int2 e2 = segp[v2 ? i2 : n - 1];
        int l1 = e1.x & 0x1FFFF;
        int l2 = e2.x & 0x1FFFF;
        float4 B1 = packs[e1.y];          // in-shard: XCD-L2 hit
        float4 B2 = packs[e2.y];
        float4 A1 = (l1 < WCAP) ? win[l1] : packs[base + l1];
        float4 A2 = (l2 < WCAP) ? win[l2] : packs[base + l2];

        float A8[8], R2v;
        if (v1 && tri_math(A1, B1, A8, R2v)) {
            int a5 = (e1.x >> 17) & (APB - 1);
            if (l1 < LFB) atomicOr(&lflag[l1 >> 5], 1u << (l1 & 31));
            else { int g = base + l1; atomicOr(&flagbits[g >> 5], 1u << (g & 31)); }
            int cand = (b << ASH) + a5;
            if (cand > __float_as_int(B1.w))          // stale .w = lower bound
                atomicMax(&pw[4 * e1.y + 3], cand);
#pragma unroll
            for (int s = 0; s < 16; ++s)
                atomicAdd(&lacc[a5 * 17 + s], A8[s & 7] * __expf(-c_eta[s] * R2v));
        }
        if (v2 && tri_math(A2, B2, A8, R2v)) {
            int a5 = (e2.x >> 17) & (APB - 1);
            if (l2 < LFB) atomicOr(&lflag[l2 >> 5], 1u << (l2 & 31));
            else { int g = base + l2; atomicOr(&flagbits[g >> 5], 1u << (g & 31)); }
            int cand = (b << ASH) + a5;
            if (cand > __float_as_int(B2.w))
                atomicMax(&pw[4 * e2.y + 3], cand);
#pragma unroll
            for (int s = 0; s < 16; ++s)
                atomicAdd(&lacc[a5 * 17 + s], A8[s & 7] * __expf(-c_eta[s] * R2v));
        }
    }
    __syncthreads();

    // merge ij-valid flags (unaligned window base -> shift into global words)
    {
        int sh = base & 31;
        int w0 = base >> 5;
        int nw = (min(pbase[b + 1] - base, LFB) + 31) >> 5;
        for (int i = thr; i < nw; i += 256) {
            unsigned int w = lflag[i];
            if (!w) continue;
            atomicOr(&flagbits[w0 + i], w << sh);
            if (sh) {
                unsigned int hi = w >> (32 - sh);
                if (hi) atomicOr(&flagbits[w0 + i + 1], hi);
            }
        }
    }
    // merge fingerprint accumulators
    for (int t = thr; t < APB * N_SF; t += 256) {
        int atom = (b << ASH) + (t >> 4);
        float v = lacc[(t >> 4) * 17 + (t & 15)];
        if (atom < N_ATOM && v != 0.0f)
            unsafeAtomicAdd(out + (size_t)atom * N_SF + (t & 15), v);
    }
}

// exact path for bucket-overflow triplets (order-free vs reduce4)
__global__ __launch_bounds__(256) void ovf3(
    const int* __restrict__ ccnt, const int2* __restrict__ ovf,
    float4* __restrict__ packs, const int* __restrict__ pbase,
    unsigned int* __restrict__ flagbits, float* __restrict__ out)
{
    int i = blockIdx.x * blockDim.x + threadIdx.x;
    int n = ccnt[OVF_CNT_IDX];
    if (n > OVF_CAP) n = OVF_CAP;
    if (i >= n) return;
    int2 e = ovf[i];
    unsigned int mij = (unsigned int)e.x;
    int qik = e.y;
    int c = mij >> 22;
    int a5 = (mij >> 17) & (APB - 1);
    int lidx = mij & 0x1FFFF;
    int qij = pbase[c] + lidx;
    float4 A = packs[qij];
    float4 B = packs[qik];
    float A8[8], R2;
    if (!tri_math(A, B, A8, R2)) return;
    int atom = (c << ASH) + a5;
    int* pw = (int*)packs;
    atomicOr(&flagbits[qij >> 5], 1u << (qij & 31));
    atomicMax(&pw[4 * qik + 3], atom);
    float* basep = out + (size_t)atom * N_SF;
#pragma unroll
    for (int s = 0; s < 16; ++s)
        unsafeAtomicAdd(basep + s, A8[s & 7] * __expf(-c_eta[s] * R2));
}

__global__ __launch_bounds__(256) void fin3(
    const unsigned int* __restrict__ amap, const int* __restrict__ pbase,
    const float4* __restrict__ packs, const unsigned int* __restrict__ flagbits,
    float* __restrict__ out)
{
    int p = blockIdx.x * blockDim.x + threadIdx.x;
    if (p >= N_PAIR) return;
    unsigned int mm = amap[p];
    int c = mm >> 22;
    int lidx = (int)(mm & 0x1FFFF);
    int a5 = (mm >> 17) & (APB - 1);
    int q = pbase[c] + lidx;
    int w = ((const int*)packs)[4 * q + 3];
    unsigned int fb = flagbits[q >> 5];
    int a = (c << ASH) + a5;
    int v = ((fb >> (q & 31)) & 1u) ? max(w, a) : w;
    float* jf = out + FP_ELEMS;
    jf[2 * p + 0] = (float)p;
    jf[2 * p + 1] = (float)v;
}

// ---------------------------------------------------------------------------
// legacy fallback
// ---------------------------------------------------------------------------

__global__ __launch_bounds__(256) void init_legacy(float* __restrict__ out) {
    int i = blockIdx.x * blockDim.x + threadIdx.x;
    if (i < FP_ELEMS) out[i] = 0.0f;
    if (i < N_PAIR) ((int*)out + FP_ELEMS)[2 * i + 1] = -1;
}

__global__ __launch_bounds__(256) void tri_legacy(
    const int* __restrict__ ind2, const int2* __restrict__ ind3,
    const float* __restrict__ dist, const float* __restrict__ diff,
    const float* __restrict__ fc, float* __restrict__ out) {
    int t = blockIdx.x * blockDim.x + threadIdx.x;
    if (t >= N_TRI) return;
    int2 pr = ind3[t];
    int ij = pr.x, ik = pr.y;
    float4 A, B;
    A.x = diff[3 * ij + 0]; A.y = diff[3 * ij + 1]; A.z = diff[3 * ij + 2]; A.w = 0.f;
    B.x = diff[3 * ik + 0]; B.y = diff[3 * ik + 1]; B.z = diff[3 * ik + 2]; B.w = 0.f;
    float A8[8], R2;
    if (!tri_math(A, B, A8, R2)) return;
    int atom = ind2[2 * ij];
    int* jac = (int*)out + FP_ELEMS;
    atomicMax(&jac[2 * ij + 1], atom);
    atomicMax(&jac[2 * ik + 1], atom);
    float* base = out + (size_t)atom * N_SF;
#pragma unroll
    for (int s = 0; s < 16; ++s)
        unsafeAtomicAdd(base + s, A8[s & 7] * __expf(-c_eta[s] * R2));
}

__global__ __launch_bounds__(256) void fin_legacy(float* __restrict__ out) {
    int p = blockIdx.x * blockDim.x + threadIdx.x;
    if (p >= N_PAIR) return;
    int* jac = (int*)out + FP_ELEMS;
    int v = jac[2 * p + 1];
    float* jf = (float*)jac;
    jf[2 * p + 0] = (float)p;
    jf[2 * p + 1] = (float)v;
}

// ---------------------------------------------------------------------------

extern "C" void kernel_launch(void* const* d_in, const int* in_sizes, int n_in,
                              void* d_out, int out_size, void* d_ws, size_t ws_size,
                              hipStream_t stream) {
    const int2*  ind2 = (const int2*)d_in[0];
    const int2*  ind3 = (const int2*)d_in[1];
    const float* dist = (const float*)d_in[2];
    const float* diff = (const float*)d_in[3];
    const float* fc   = (const float*)d_in[5];
    float* out = (float*)d_out;

    const size_t seg_stride = (size_t)NSEG * sizeof(int2);
    const size_t need_min = OFF_CB + seg_stride * 608;

    if (ws_size >= need_min) {
        char* ws = (char*)d_ws;
        int* ccnt            = (int*)(ws + OFF_CCNT);
        int* pcnt            = (int*)(ws + OFF_PCNT);
        int* pplace          = (int*)(ws + OFF_PPLACE);
        int* pbase           = (int*)(ws + OFF_PBASE);
        unsigned int* amap   = (unsigned int*)(ws + OFF_AMAP);
        unsigned int* flagb  = (unsigned int*)(ws + OFF_FLAGB);
        int2* ovf            = (int2*)(ws + OFF_OVF);
        float4* packs        = (float4*)(ws + OFF_PACKS);
        int2* cbucket        = (int2*)(ws + OFF_CB);
        int cap = (int)((ws_size - OFF_CB) / seg_stride);
        if (cap > 1024) cap = 1024;

        int pb = (N_PAIR + 255) / 256;
        zero_meta<<<(ZERO_INTS + 255) / 256, 256, 0, stream>>>((int*)ws, flagb);
        pair_hist<<<240, 256, 0, stream>>>(ind2, pcnt);
        scan_bases<<<1, 1024, 0, stream>>>(pcnt, pbase);
        pair_place<<<pb, 256, 0, stream>>>(ind2, diff, pbase, pplace, amap, packs, out);
        bin3<<<NTILES, 256, 0, stream>>>(ind3, amap, pbase, ccnt, cbucket, ovf, cap);
        reduce4<<<NSEG, 256, 0, stream>>>(ccnt, cbucket, cap, packs, pbase, flagb, out);
        ovf3<<<OVF_CAP / 256, 256, 0, stream>>>(ccnt, ovf, packs, pbase, flagb, out);
        fin3<<<pb, 256, 0, stream>>>(amap, pbase, packs, flagb, out);
    } else {
        init_legacy<<<(N_PAIR + 255) / 256, 256, 0, stream>>>(out);
        tri_legacy<<<(N_TRI + 255) / 256, 256, 0, stream>>>((const int*)d_in[0], ind3, dist, diff, fc, out);
        fin_legacy<<<(N_PAIR + 255) / 256, 256, 0, stream>>>(out);
    }
    (void)dist; (void)fc; (void)in_sizes; (void)n_in; (void)out_size;
}

// Round 6
// 443.186 us; speedup vs baseline: 1.2749x; 1.2749x over previous
//
#include <hip/hip_runtime.h>

#define N_ATOM 30000
#define N_PAIR 1000000
#define N_TRI  4000000
#define N_SF   16
#define FP_ELEMS (N_ATOM * N_SF)

#define ASH  5                      // atoms per coarse bucket = 32
#define APB  32
#define NCB  938                    // ceil(30000/32)
#define NSUB 8                      // XCD sub-buckets
#define NSEG (NCB * NSUB)           // 7504
#define OVF_CNT_IDX NSEG
#define OVF_CAP 131072
#define TILE 4096
#define PER_TH 16
#define NTILES ((N_TRI + TILE - 1) / TILE)   // 977
#define NWAVE 4                     // waves per block (256 threads)

// workspace layout (bytes)  — identical to the verified 445.7us baseline
#define OFF_CCNT  0ULL              //  32 KiB: NSEG+1 ints
#define OFF_IKMAX 65536ULL          //  4,000,000  (int per pair)
#define OFF_AOFP  4065536ULL        //  2,000,000  (ushort per pair)
#define OFF_FLAG  6065536ULL        //  1,000,000  (byte per pair)
#define OFF_OVF   7065536ULL        //  1,048,576  (int2 * 131072)
#define OFF_PACK  8114112ULL        // 16,000,000  (float4 {dx,dy,dz,fc})
#define OFF_CB    24114112ULL       // cbucket: NSEG * cap * 8

// ---------------------------------------------------------------------------
__device__ __forceinline__ bool tri_math_pack(
    float4 A, float4 B, float A8[8], float& R2)
{
    float ax = A.x, ay = A.y, az = A.z, fcij = A.w;
    float bx = B.x, by = B.y, bz = B.z, fcik = B.w;
    float d2ij = fmaf(ax, ax, fmaf(ay, ay, az * az));
    float d2ik = fmaf(bx, bx, fmaf(by, by, bz * bz));
    float jx = bx - ax, jy = by - ay, jz = bz - az;
    float d2jk = fmaf(jx, jx, fmaf(jy, jy, jz * jz));
    if (!(d2jk < 36.0f)) return false;
    float dij = sqrtf(d2ij);
    float dik = sqrtf(d2ik);
    float djk = sqrtf(d2jk);
    const float PI_OVER_RC = 0.5235987755982988f;
    float fcjk = 0.5f * (__cosf(PI_OVER_RC * djk) + 1.0f);
    float dot = fmaf(ax, bx, fmaf(ay, by, az * bz));
    float cosv = dot / (dij * dik);
    R2 = d2ij + d2ik + d2jk;
    float FCt = fcij * fcik * fcjk;
    float bm = fmaxf(1.0f - cosv, 0.0f);
    float bp = fmaxf(1.0f + cosv, 0.0f);
    float bm2 = bm * bm, bp2 = bp * bp;
    float bm4 = bm2 * bm2, bp4 = bp2 * bp2;
    float bm8 = bm4 * bm4, bp8 = bp4 * bp4;
    A8[0] = FCt * bm;              A8[1] = FCt * bp;
    A8[2] = 0.5f * FCt * bm2;      A8[3] = 0.5f * FCt * bp2;
    A8[4] = 0.125f * FCt * bm4;    A8[5] = 0.125f * FCt * bp4;
    A8[6] = 0.0078125f * FCt * bm8; A8[7] = 0.0078125f * FCt * bp8;
    return true;
}

// exp(-eta_s * R2) for all 16 eta via 4 expf + exact x2/sum chains:
// eta = {.01,.014,.02,.028,.04,.056,.08,.11,.16,.22,.32,.45,.63,.72,.9,1.}
// chains: .01->.02->.04->.08->.16->.32 ; .014->.028->.056 ; .11->.22 ;
// .45->.9 ; .63=.45+.16+.02 ; .72=.32*2+.08 ; 1.0=.9+.08+.02
#define SF_ACCUM(lrow, A8, R2, ATOMIC) do {                                   \
    float e0  = __expf(-0.01f  * (R2));                                       \
    float e1  = __expf(-0.014f * (R2));                                       \
    float e7  = __expf(-0.11f  * (R2));                                       \
    float e11 = __expf(-0.45f  * (R2));                                       \
    float e2 = e0*e0,  e3 = e1*e1;                                            \
    float e4 = e2*e2,  e5 = e3*e3;                                            \
    float e6 = e4*e4,  e9 = e7*e7;                                            \
    float e8 = e6*e6,  e14 = e11*e11;                                         \
    float e10 = e8*e8;                                                        \
    float e12 = e11*e8*e2;                                                    \
    float e13 = e10*e10*e6;                                                   \
    float e15 = e14*e6*e2;                                                    \
    ATOMIC(&(lrow)[0],  (A8)[0]*e0);  ATOMIC(&(lrow)[1],  (A8)[1]*e1);        \
    ATOMIC(&(lrow)[2],  (A8)[2]*e2);  ATOMIC(&(lrow)[3],  (A8)[3]*e3);        \
    ATOMIC(&(lrow)[4],  (A8)[4]*e4);  ATOMIC(&(lrow)[5],  (A8)[5]*e5);        \
    ATOMIC(&(lrow)[6],  (A8)[6]*e6);  ATOMIC(&(lrow)[7],  (A8)[7]*e7);        \
    ATOMIC(&(lrow)[8],  (A8)[0]*e8);  ATOMIC(&(lrow)[9],  (A8)[1]*e9);        \
    ATOMIC(&(lrow)[10], (A8)[2]*e10); ATOMIC(&(lrow)[11], (A8)[3]*e11);       \
    ATOMIC(&(lrow)[12], (A8)[4]*e12); ATOMIC(&(lrow)[13], (A8)[5]*e13);       \
    ATOMIC(&(lrow)[14], (A8)[6]*e14); ATOMIC(&(lrow)[15], (A8)[7]*e15);       \
} while (0)

#define ATOM_LDS(p, v)  atomicAdd((p), (v))
#define ATOM_GLB(p, v)  unsafeAtomicAdd((p), (v))

// ---------------------------------------------------------------------------
// fast path
// ---------------------------------------------------------------------------

__global__ __launch_bounds__(256) void prep2(
    const int2* __restrict__ ind2, const float* __restrict__ diff,
    const float* __restrict__ fc,
    int* __restrict__ ccnt, int* __restrict__ ikmax,
    unsigned short* __restrict__ aofp, unsigned char* __restrict__ flag,
    float4* __restrict__ pack, float* __restrict__ out)
{
    int p = blockIdx.x * blockDim.x + threadIdx.x;
    if (p <= NSEG) ccnt[p] = 0;     // includes overflow counter
    if (p < FP_ELEMS) out[p] = 0.0f;  // zero fp rows (reduce4/ovf3 atomic-add)
    if (p >= N_PAIR) return;
    ikmax[p] = -1;
    flag[p] = 0;
    aofp[p] = (unsigned short)ind2[p].x;
    float4 r;
    r.x = diff[3 * p + 0];
    r.y = diff[3 * p + 1];
    r.z = diff[3 * p + 2];
    r.w = fc[p];
    pack[p] = r;
}

// LDS-staged counting scatter into coarse buckets (XCD sub-bucketed).
__global__ __launch_bounds__(256) void bin3(
    const int2* __restrict__ ind3, const unsigned short* __restrict__ aofp,
    int* __restrict__ ccnt, int2* __restrict__ cbucket,
    int2* __restrict__ ovf, int cap)
{
    __shared__ int lcnt[NCB];
    __shared__ int lbase[NCB];
    const int thr = threadIdx.x;
    const int sub = blockIdx.x & (NSUB - 1);
    const long long t0 = (long long)blockIdx.x * TILE;

    for (int i = thr; i < NCB; i += 256) lcnt[i] = 0;
    __syncthreads();

    int myatom[PER_TH];
    int myslot[PER_TH];
#pragma unroll
    for (int j = 0; j < PER_TH; ++j) {
        long long t = t0 + j * 256 + thr;
        int a = 0, s = -1;
        if (t < N_TRI) {
            int ij = ind3[t].x;
            a = aofp[ij];
            s = atomicAdd(&lcnt[a >> ASH], 1);
        }
        myatom[j] = a;
        myslot[j] = s;
    }
    __syncthreads();
    for (int c = thr; c < NCB; c += 256) {
        int n = lcnt[c];
        lbase[c] = n ? atomicAdd(&ccnt[c * NSUB + sub], n) : 0;
    }
    __syncthreads();
#pragma unroll
    for (int j = 0; j < PER_TH; ++j) {
        long long t = t0 + j * 256 + thr;
        if (t >= N_TRI) continue;
        int a = myatom[j];
        int c = a >> ASH;
        int slot = lbase[c] + myslot[j];
        int2 pr = ind3[t];
        if (slot < cap) {
            int2 e;
            e.x = pr.x | ((a & (APB - 1)) << 20);   // ij < 2^20, pack a5 above
            e.y = pr.y;
            cbucket[(size_t)(c * NSUB + sub) * cap + slot] = e;
        } else {
            int o = atomicAdd(&ccnt[OVF_CNT_IDX], 1);
            if (o < OVF_CAP) ovf[o] = pr;
        }
    }
}

// one block per (coarse bucket, sub) segment: 7504 blocks, ~533 triplets each.
// PROBE: per-wave replicated LDS accumulators (cross-wave same-address DS
// atomic serialization was the one untouched invariant across 6 flat rounds)
// + 4-exp chained gaussian basis (was 16 expf on the quarter-rate trans pipe).
__global__ __launch_bounds__(256) void reduce4(
    const int* __restrict__ ccnt, const int2* __restrict__ cbucket, int cap,
    const float4* __restrict__ pack,
    int* __restrict__ ikmax, unsigned char* __restrict__ flag,
    float* __restrict__ out)
{
    __shared__ float lacc[NWAVE][APB * 17];   // per-wave replicas, +1 pad/row
    const int seg = blockIdx.x;
    const int b = seg >> 3;               // coarse bucket
    const int thr = threadIdx.x;
    const int wid = thr >> 6;
    for (int i = thr; i < NWAVE * APB * 17; i += 256)
        ((float*)lacc)[i] = 0.0f;
    __syncthreads();

    int n = ccnt[seg];
    n = min(n, cap);
    const int2* segp = cbucket + (size_t)seg * cap;
    for (int i = thr; i < n; i += 256) {
        int2 e = segp[i];
        int a5 = (e.x >> 20) & (APB - 1);
        int ij = e.x & 0xFFFFF;
        int ik = e.y;
        float4 A = pack[ij];
        float4 B = pack[ik];
        float A8[8], R2;
        if (!tri_math_pack(A, B, A8, R2)) continue;
        flag[ij] = 1;
        atomicMax(&ikmax[ik], (b << ASH) + a5);
        float* lrow = &lacc[wid][a5 * 17];
        SF_ACCUM(lrow, A8, R2, ATOM_LDS);
    }
    __syncthreads();
    for (int t = thr; t < APB * N_SF; t += 256) {
        int atom = (b << ASH) + (t >> 4);
        int idx = (t >> 4) * 17 + (t & 15);
        float v = lacc[0][idx] + lacc[1][idx] + lacc[2][idx] + lacc[3][idx];
        if (atom < N_ATOM && v != 0.0f)
            unsafeAtomicAdd(out + (size_t)atom * N_SF + (t & 15), v);
    }
}

// exact path for bucket-overflow triplets (atomic adds; order-free vs reduce4)
__global__ __launch_bounds__(256) void ovf3(
    const int* __restrict__ ccnt, const int2* __restrict__ ovf,
    const float4* __restrict__ pack, const unsigned short* __restrict__ aofp,
    int* __restrict__ ikmax, unsigned char* __restrict__ flag,
    float* __restrict__ out)
{
    int i = blockIdx.x * blockDim.x + threadIdx.x;
    int n = ccnt[OVF_CNT_IDX];
    if (n > OVF_CAP) n = OVF_CAP;
    if (i >= n) return;
    int2 pr = ovf[i];
    int ij = pr.x, ik = pr.y;
    float A8[8], R2;
    if (!tri_math_pack(pack[ij], pack[ik], A8, R2)) return;
    int atom = aofp[ij];
    flag[ij] = 1;
    atomicMax(&ikmax[ik], atom);
    float* base = out + (size_t)atom * N_SF;
    SF_ACCUM(base, A8, R2, ATOM_GLB);
}

__global__ __launch_bounds__(256) void fin3(
    const int* __restrict__ ikmax, const unsigned char* __restrict__ flag,
    const unsigned short* __restrict__ aofp, float* __restrict__ out)
{
    int p = blockIdx.x * blockDim.x + threadIdx.x;
    if (p >= N_PAIR) return;
    int v = ikmax[p];
    if (flag[p]) { int a = aofp[p]; v = v > a ? v : a; }
    float* jf = out + FP_ELEMS;
    jf[2 * p + 0] = (float)p;
    jf[2 * p + 1] = (float)v;
}

// ---------------------------------------------------------------------------
// legacy fallback
// ---------------------------------------------------------------------------

__global__ __launch_bounds__(256) void init_legacy(float* __restrict__ out) {
    int i = blockIdx.x * blockDim.x + threadIdx.x;
    if (i < FP_ELEMS) out[i] = 0.0f;
    if (i < N_PAIR) ((int*)out + FP_ELEMS)[2 * i + 1] = -1;
}

__global__ __launch_bounds__(256) void tri_legacy(
    const int* __restrict__ ind2, const int2* __restrict__ ind3,
    const float* __restrict__ dist, const float* __restrict__ diff,
    const float* __restrict__ fc, float* __restrict__ out) {
    int t = blockIdx.x * blockDim.x + threadIdx.x;
    if (t >= N_TRI) return;
    int2 pr = ind3[t];
    int ij = pr.x, ik = pr.y;
    float4 A, B;
    A.x = diff[3 * ij + 0]; A.y = diff[3 * ij + 1]; A.z = diff[3 * ij + 2]; A.w = fc[ij];
    B.x = diff[3 * ik + 0]; B.y = diff[3 * ik + 1]; B.z = diff[3 * ik + 2]; B.w = fc[ik];
    float A8[8], R2;
    if (!tri_math_pack(A, B, A8, R2)) return;
    int atom = ind2[2 * ij];
    int* jac = (int*)out + FP_ELEMS;
    atomicMax(&jac[2 * ij + 1], atom);
    atomicMax(&jac[2 * ik + 1], atom);
    float* base = out + (size_t)atom * N_SF;
    SF_ACCUM(base, A8, R2, ATOM_GLB);
}

__global__ __launch_bounds__(256) void fin_legacy(float* __restrict__ out) {
    int p = blockIdx.x * blockDim.x + threadIdx.x;
    if (p >= N_PAIR) return;
    int* jac = (int*)out + FP_ELEMS;
    int v = jac[2 * p + 1];
    float* jf = (float*)jac;
    jf[2 * p + 0] = (float)p;
    jf[2 * p + 1] = (float)v;
}

// ---------------------------------------------------------------------------

extern "C" void kernel_launch(void* const* d_in, const int* in_sizes, int n_in,
                              void* d_out, int out_size, void* d_ws, size_t ws_size,
                              hipStream_t stream) {
    const int2*  ind2 = (const int2*)d_in[0];
    const int2*  ind3 = (const int2*)d_in[1];
    const float* dist = (const float*)d_in[2];
    const float* diff = (const float*)d_in[3];
    const float* fc   = (const float*)d_in[5];
    float* out = (float*)d_out;

    const size_t seg_stride = (size_t)NSEG * sizeof(int2);
    const size_t need_min = OFF_CB + seg_stride * 608;

    if (ws_size >= need_min) {
        char* ws = (char*)d_ws;
        int* ccnt            = (int*)(ws + OFF_CCNT);
        int* ikmax           = (int*)(ws + OFF_IKMAX);
        unsigned short* aofp = (unsigned short*)(ws + OFF_AOFP);
        unsigned char* flag  = (unsigned char*)(ws + OFF_FLAG);
        int2* ovf            = (int2*)(ws + OFF_OVF);
        float4* pack         = (float4*)(ws + OFF_PACK);
        int2* cbucket        = (int2*)(ws + OFF_CB);
        int cap = (int)((ws_size - OFF_CB) / seg_stride);
        if (cap > 1024) cap = 1024;

        int pb = (N_PAIR + 255) / 256;
        prep2<<<pb, 256, 0, stream>>>(ind2, diff, fc, ccnt, ikmax, aofp, flag, pack, out);
        bin3<<<NTILES, 256, 0, stream>>>(ind3, aofp, ccnt, cbucket, ovf, cap);
        reduce4<<<NSEG, 256, 0, stream>>>(ccnt, cbucket, cap, pack, ikmax, flag, out);
        ovf3<<<OVF_CAP / 256, 256, 0, stream>>>(ccnt, ovf, pack, aofp, ikmax, flag, out);
        fin3<<<pb, 256, 0, stream>>>(ikmax, flag, aofp, out);
    } else {
        init_legacy<<<(N_PAIR + 255) / 256, 256, 0, stream>>>(out);
        tri_legacy<<<(N_PAIR * 4 + 255) / 256, 256, 0, stream>>>((const int*)d_in[0], ind3, dist, diff, fc, out);
        fin_legacy<<<(N_PAIR + 255) / 256, 256, 0, stream>>>(out);
    }
    (void)dist; (void)in_sizes; (void)n_in; (void)out_size;
}